// Round 5
// baseline (203.147 us; speedup 1.0000x reference)
//
#include <hip/hip_runtime.h>
#include <stdint.h>

typedef _Float16 f16;
typedef __attribute__((ext_vector_type(8))) _Float16 f16x8;
typedef __attribute__((ext_vector_type(4))) float f32x4;
typedef __attribute__((ext_vector_type(2))) unsigned int u32x2;
typedef __attribute__((ext_vector_type(4))) unsigned int u32x4;
typedef decltype(__builtin_amdgcn_cvt_pkrtz(0.f, 0.f)) h2_t;

#define S_LEN 2048
#define BATCH 8
#define D_IN  1024
#define DHALF 512

__device__ __forceinline__ unsigned lds_off(const void* p) {
  return (unsigned)(size_t)p;
}

// async global->LDS DMA, 16B per lane. LDS dest is wave-uniform base (+lane*16 by HW).
__device__ __forceinline__ void dma16(const void* g, void* lds_uniform) {
  __builtin_amdgcn_global_load_lds(
      (const __attribute__((address_space(1))) void*)g,
      (__attribute__((address_space(3))) void*)lds_uniform, 16, 0, 0);
}

// ---------------------------------------------------------------------------
// W f32 -> f16 preconvert (one-shot, ~3MB): out[z] = (f16)W[z], layout [n][k].
// ---------------------------------------------------------------------------
__global__ __launch_bounds__(256) void wcvt_kernel(
    const float* __restrict__ Wq, const float* __restrict__ Wk, const float* __restrict__ Wv,
    f16* __restrict__ out)
{
  const int z = blockIdx.y;
  const float* W = (z == 0) ? Wq : (z == 1) ? Wk : Wv;
  const int idx = (blockIdx.x * 256 + threadIdx.x) * 8;
  f32x4 a = *(const f32x4*)(W + idx);
  f32x4 b = *(const f32x4*)(W + idx + 4);
  union { h2_t h2[4]; f16x8 v; } u;
  u.h2[0] = __builtin_amdgcn_cvt_pkrtz(a.x, a.y);
  u.h2[1] = __builtin_amdgcn_cvt_pkrtz(a.z, a.w);
  u.h2[2] = __builtin_amdgcn_cvt_pkrtz(b.x, b.y);
  u.h2[3] = __builtin_amdgcn_cvt_pkrtz(b.z, b.w);
  *(f16x8*)(out + (size_t)z * (DHALF * D_IN) + idx) = u.v;
}

// ---------------------------------------------------------------------------
// Projection: out[s,b,e] = sum_d X[s,b,d] * W[e,d] + bias[e], stored fp16.
// Tile 128x128x32, 4 waves, 64x64/wave. global_load_lds DMA staging,
// TRIPLE-buffered with COUNTED vmcnt (T4, m201 recipe):
//   iter k: s_waitcnt vmcnt(6)  (set k done; set k+1 in flight)
//           s_barrier
//           ISSUE set k+2 into buf freed by compute(k-1)
//           COMPUTE(k)
// Never drains to 0 in the main loop -> each DMA set gets ~2 K-steps of cover.
// A staged f32 w/ source-swizzle byte^=(row&7)<<4; B f16 w/ byte^=((row>>1)&3)<<4.
// ---------------------------------------------------------------------------
__global__ __launch_bounds__(256, 2) void proj_kernel(
    const float* __restrict__ Xq, const float* __restrict__ Xk, const float* __restrict__ Xv,
    const f16* __restrict__ Wf16,
    const float* __restrict__ bq, const float* __restrict__ bk, const float* __restrict__ bv,
    f16* __restrict__ oq, f16* __restrict__ ok, f16* __restrict__ ov)
{
  const int z = blockIdx.z;
  const float* X    = (z == 0) ? Xq : (z == 1) ? Xk : Xv;
  const f16*   W    = Wf16 + (size_t)z * (DHALF * D_IN);
  const float* bias = (z == 0) ? bq : (z == 1) ? bk : bv;
  f16* out          = (z == 0) ? oq : (z == 1) ? ok : ov;

  const int m0 = blockIdx.x * 128;
  const int n0 = blockIdx.y * 128;
  const int tid = threadIdx.x;
  const int lane = tid & 63;
  const int wave = tid >> 6;
  const int wr = wave >> 1, wc = wave & 1;
  const int g = lane >> 4, rl = lane & 15;

  __shared__ float As[3][4096];   // 3 x 16KB: [128 rows][32 k f32], source-swizzled
  __shared__ f16   Bs[3][4096];   // 3 x  8KB: [128 rows][32 k f16], source-swizzled

  f32x4 acc[4][4];
#pragma unroll
  for (int i = 0; i < 4; i++)
#pragma unroll
    for (int j = 0; j < 4; j++) acc[i][j] = (f32x4){0.f, 0.f, 0.f, 0.f};

  // ---- DMA source/dest precompute (6 DMA per wave per K-step: 4 A + 2 B) ----
  const char* gaA[4];
  unsigned    ldA[4];
#pragma unroll
  for (int i = 0; i < 4; i++) {
    unsigned L   = wave * 4096 + i * 1024 + lane * 16;
    unsigned row = L >> 7;
    unsigned col = (L ^ ((row & 7) << 4)) & 127;
    gaA[i] = (const char*)X + (size_t)(m0 + row) * (D_IN * 4) + col;
    ldA[i] = wave * 4096 + i * 1024;
  }
  const char* gaB[2];
  unsigned    ldB[2];
#pragma unroll
  for (int i = 0; i < 2; i++) {
    unsigned L   = wave * 2048 + i * 1024 + lane * 16;
    unsigned row = L >> 6;
    unsigned col = (L ^ (((row >> 1) & 3) << 4)) & 63;
    gaB[i] = (const char*)W + (size_t)(n0 + row) * (D_IN * 2) + col;
    ldB[i] = wave * 2048 + i * 1024;
  }

#define ISSUE(BUF, KSTEP) {                                                   \
  char* abase = (char*)&As[0][0] + (unsigned)(BUF) * 16384u;                  \
  char* bbase = (char*)&Bs[0][0] + (unsigned)(BUF) * 8192u;                   \
  _Pragma("unroll")                                                           \
  for (int i = 0; i < 4; i++)                                                 \
    dma16(gaA[i] + (KSTEP) * 128, abase + ldA[i]);                            \
  _Pragma("unroll")                                                           \
  for (int i = 0; i < 2; i++)                                                 \
    dma16(gaB[i] + (KSTEP) * 64,  bbase + ldB[i]); }

#define PCOMPUTE(BUF) {                                                       \
  const char* abase = (const char*)&As[0][0] + (unsigned)(BUF) * 16384u;      \
  const char* bbase = (const char*)&Bs[0][0] + (unsigned)(BUF) * 8192u;       \
  f16x8 bf[4];                                                                \
  _Pragma("unroll")                                                           \
  for (int j = 0; j < 4; j++) {                                               \
    unsigned row = wc * 64 + j * 16 + rl;                                     \
    unsigned off = row * 64 + ((g * 16) ^ (((rl >> 1) & 3) << 4));            \
    bf[j] = *(const f16x8*)(bbase + off);                                     \
  }                                                                           \
  f16x8 af[4];                                                                \
  _Pragma("unroll")                                                           \
  for (int i = 0; i < 4; i++) {                                               \
    unsigned row = wr * 64 + i * 16 + rl;                                     \
    unsigned off = row * 128 + ((g * 32) ^ ((rl & 7) << 4));                  \
    f32x4 lo = *(const f32x4*)(abase + off);                                  \
    f32x4 hi = *(const f32x4*)(abase + (off ^ 16));                           \
    union { h2_t h2[4]; f16x8 v; } u;                                         \
    u.h2[0] = __builtin_amdgcn_cvt_pkrtz(lo.x, lo.y);                         \
    u.h2[1] = __builtin_amdgcn_cvt_pkrtz(lo.z, lo.w);                         \
    u.h2[2] = __builtin_amdgcn_cvt_pkrtz(hi.x, hi.y);                         \
    u.h2[3] = __builtin_amdgcn_cvt_pkrtz(hi.z, hi.w);                         \
    af[i] = u.v;                                                              \
  }                                                                           \
  _Pragma("unroll")                                                           \
  for (int i = 0; i < 4; i++)                                                 \
    _Pragma("unroll")                                                         \
    for (int j = 0; j < 4; j++)                                               \
      acc[i][j] = __builtin_amdgcn_mfma_f32_16x16x32_f16(af[i], bf[j], acc[i][j], 0, 0, 0); }

  // prologue: sets 0,1 in flight (12 DMA/wave)
  ISSUE(0, 0);
  ISSUE(1, 1);

  int cb = 0;   // compute buffer for step k
  int ib = 2;   // issue buffer for step k+2
  for (int k = 0; k < 32; ++k) {
    if (k < 31) { asm volatile("s_waitcnt vmcnt(6)" ::: "memory"); }  // set k done
    else        { asm volatile("s_waitcnt vmcnt(0)" ::: "memory"); }  // tail drain
    __builtin_amdgcn_s_barrier();
    __builtin_amdgcn_sched_barrier(0);
    if (k + 2 < 32) {
      ISSUE(ib, k + 2);                   // buf freed by compute(k-1)
      ib = (ib == 2) ? 0 : ib + 1;
    }
    PCOMPUTE(cb);
    cb = (cb == 2) ? 0 : cb + 1;
  }
#undef ISSUE
#undef PCOMPUTE

  // epilogue: + bias, cast fp16; C/D layout: col = lane&15, row = (lane>>4)*4 + r
#pragma unroll
  for (int i = 0; i < 4; i++) {
    const int row = m0 + wr * 64 + i * 16 + g * 4;
#pragma unroll
    for (int j = 0; j < 4; j++) {
      const int col = n0 + wc * 64 + j * 16 + rl;
      const float bb = bias[col];
#pragma unroll
      for (int r = 0; r < 4; r++)
        out[(size_t)(row + r) * DHALF + col] = (f16)(acc[i][j][r] + bb);
    }
  }
}

// ---------------------------------------------------------------------------
// Batched GEMM-TN: C[b] = A[b] (M x K, K-contig) * B[b] (K x N, N-contig).
// Template MI = M-fragments per wave (4 -> BM=128, 2 -> BM=64).
// B transpose-staged into [4k][16n] subtiles, phys order {0,2,4,6,1,3,5,7},
// read via ds_read_b64_tr_b16 (+offset:512).
// EPI=0: apply attn mask, store f32 logits.  EPI=1: store f32 to out.
// ---------------------------------------------------------------------------
template <int EPI, int MI>
__global__ __launch_bounds__(256, 3) void gemm_tn_kernel(
    const f16* __restrict__ A, long batchA, int lda,
    const f16* __restrict__ Bm, long batchB, int ldb,
    int Ksize,
    const int* __restrict__ mask,
    float* __restrict__ out, long batchOut, int ldo)
{
  constexpr int BM = MI * 32;            // block M-tile
  const int bz = blockIdx.z;
  const int n0 = blockIdx.x * 128;
  const int m0 = blockIdx.y * BM;
  const f16* Ab = A + (size_t)bz * batchA;
  const f16* Bb = Bm + (size_t)bz * batchB;

  const int tid = threadIdx.x, lane = tid & 63, wave = tid >> 6;
  const int wr = wave >> 1, wc = wave & 1;
  const int g = lane >> 4, rl = lane & 15;

  __shared__ f16 As[2][BM * 40];         // padded stride 40
  __shared__ f16 Bs[2][32 * 128];        // [n_blk(8)][phys(8)] blocks of [4][16]

  f32x4 acc[MI][4];
#pragma unroll
  for (int i = 0; i < MI; i++)
#pragma unroll
    for (int j = 0; j < 4; j++) acc[i][j] = (f32x4){0.f, 0.f, 0.f, 0.f};

  // A staging: BM*32 f16 by 256 threads
  const int arow = (MI == 4) ? (tid >> 1) : (tid >> 2);
  const int ah   = (MI == 4) ? ((tid & 1) * 16) : ((tid & 3) * 8);
  const int brow = tid >> 3;             // k-row 0..31
  const int bcol = (tid & 7) * 16;       // n offset
  const int sblk = brow >> 2;
  const int phys = ((sblk & 1) << 2) | (sblk >> 1);
  const int bwoff = ((tid & 7) * 8 + phys) * 128 + (brow & 3) * 32;  // bytes
  const f16* gA = Ab + (size_t)(m0 + arow) * lda + ah;
  const f16* gB = Bb + (size_t)brow * ldb + n0 + bcol;

  const unsigned bs_base = lds_off(&Bs[0][0]);

  f16x8 va0, va1, vb0, vb1;

#define GLOAD(K0)                                                       \
  va0 = *(const f16x8*)(gA + (K0));                                     \
  if (MI == 4) va1 = *(const f16x8*)(gA + (K0) + 8);                    \
  { const f16* gb = gB + (size_t)(K0) * ldb;                            \
    vb0 = *(const f16x8*)(gb);                                          \
    vb1 = *(const f16x8*)(gb + 8); }

#define GWRITE(BUF) {                                                   \
  *(f16x8*)&As[BUF][arow * 40 + ah] = va0;                              \
  if (MI == 4) *(f16x8*)&As[BUF][arow * 40 + ah + 8] = va1;             \
  char* wb = (char*)&Bs[BUF][0] + bwoff;                                \
  *(f16x8*)wb        = vb0;                                             \
  *(f16x8*)(wb + 16) = vb1; }

  GLOAD(0);
  GWRITE(0);
  __syncthreads();

  int cur = 0;
#pragma unroll 2
  for (int k0 = 0; k0 < Ksize; k0 += 32) {
    const bool more = (k0 + 32 < Ksize);
    if (more) { GLOAD(k0 + 32); }

    f16x8 af[MI];
#pragma unroll
    for (int i = 0; i < MI; i++)
      af[i] = *(const f16x8*)&As[cur][(wr * (MI * 16) + i * 16 + rl) * 40 + g * 8];

    f16x8 bf[4];
#pragma unroll
    for (int j = 0; j < 4; j++) {
      unsigned addr = bs_base + (unsigned)cur * 8192u +
                      (unsigned)((wc * 4 + j) * 1024) + (unsigned)lane * 8u;
      u32x2 lo, hi;
      asm volatile("ds_read_b64_tr_b16 %0, %1" : "=v"(lo) : "v"(addr));
      asm volatile("ds_read_b64_tr_b16 %0, %1 offset:512" : "=v"(hi) : "v"(addr));
      union { u32x4 u; f16x8 h; } cc;
      cc.u = (u32x4){lo.x, lo.y, hi.x, hi.y};
      bf[j] = cc.h;
    }
    // rule 18: fence tr-read results before register-only MFMA consumers
    asm volatile("s_waitcnt lgkmcnt(0)" ::: "memory");
    __builtin_amdgcn_sched_barrier(0);

#pragma unroll
    for (int i = 0; i < MI; i++)
#pragma unroll
      for (int j = 0; j < 4; j++)
        acc[i][j] = __builtin_amdgcn_mfma_f32_16x16x32_f16(af[i], bf[j], acc[i][j], 0, 0, 0);

    if (more) {
      GWRITE(cur ^ 1);
      __syncthreads();
      cur ^= 1;
    }
  }
#undef GLOAD
#undef GWRITE

  float* ob = out + (size_t)bz * batchOut;
#pragma unroll
  for (int i = 0; i < MI; i++) {
    const int row = m0 + wr * (MI * 16) + i * 16 + g * 4;
#pragma unroll
    for (int j = 0; j < 4; j++) {
      const int col = n0 + wc * 64 + j * 16 + rl;
#pragma unroll
      for (int r = 0; r < 4; r++) {
        float val = acc[i][j][r];
        if (EPI == 0) {
          if (mask[(row + r) * DHALF + col] != 0) val = -1e30f;
        }
        ob[(size_t)(row + r) * ldo + col] = val;
      }
    }
  }
}

// ---------------------------------------------------------------------------
// Row softmax over e (512) for 4096 rows; one wave per row; fp16 output.
// ---------------------------------------------------------------------------
__global__ __launch_bounds__(256) void softmax_kernel(
    const float* __restrict__ logits, f16* __restrict__ P)
{
  const int row  = blockIdx.x * 4 + (threadIdx.x >> 6);
  const int lane = threadIdx.x & 63;
  const float* rp = logits + (size_t)row * DHALF + lane * 8;
  f32x4 x0 = *(const f32x4*)rp;
  f32x4 x1 = *(const f32x4*)(rp + 4);

  float m = fmaxf(fmaxf(fmaxf(x0.x, x0.y), fmaxf(x0.z, x0.w)),
                  fmaxf(fmaxf(x1.x, x1.y), fmaxf(x1.z, x1.w)));
#pragma unroll
  for (int off = 32; off > 0; off >>= 1) m = fmaxf(m, __shfl_xor(m, off, 64));

  float e0 = __expf(x0.x - m), e1 = __expf(x0.y - m);
  float e2 = __expf(x0.z - m), e3 = __expf(x0.w - m);
  float e4 = __expf(x1.x - m), e5 = __expf(x1.y - m);
  float e6 = __expf(x1.z - m), e7 = __expf(x1.w - m);
  float s = ((e0 + e1) + (e2 + e3)) + ((e4 + e5) + (e6 + e7));
#pragma unroll
  for (int off = 32; off > 0; off >>= 1) s += __shfl_xor(s, off, 64);
  const float inv = 1.0f / s;

  union { h2_t h2[4]; f16x8 v; } o;
  o.h2[0] = __builtin_amdgcn_cvt_pkrtz(e0 * inv, e1 * inv);
  o.h2[1] = __builtin_amdgcn_cvt_pkrtz(e2 * inv, e3 * inv);
  o.h2[2] = __builtin_amdgcn_cvt_pkrtz(e4 * inv, e5 * inv);
  o.h2[3] = __builtin_amdgcn_cvt_pkrtz(e6 * inv, e7 * inv);
  *(f16x8*)(P + (size_t)row * DHALF + lane * 8) = o.v;
}

// ---------------------------------------------------------------------------
extern "C" void kernel_launch(void* const* d_in, const int* in_sizes, int n_in,
                              void* d_out, int out_size, void* d_ws, size_t ws_size,
                              hipStream_t stream) {
  const float* q    = (const float*)d_in[0];
  const float* k    = (const float*)d_in[1];
  const float* v    = (const float*)d_in[2];
  const int*   mask = (const int*)d_in[3];
  const float* Wq   = (const float*)d_in[4];
  const float* bq   = (const float*)d_in[5];
  const float* Wk   = (const float*)d_in[6];
  const float* bk   = (const float*)d_in[7];
  const float* Wv   = (const float*)d_in[8];
  const float* bv   = (const float*)d_in[9];

  char* ws = (char*)d_ws;
  f16*   qt     = (f16*)(ws);                                  // 16 MB
  f16*   kt     = (f16*)(ws + 16777216);                       // 16 MB
  f16*   vt     = (f16*)(ws + 2 * 16777216);                   // 16 MB
  float* logits = (float*)(ws + 3 * 16777216);                 // 8 MB
  f16*   P      = (f16*)(ws + 3 * 16777216 + 8388608);         // 4 MB
  // Wf16 (3 MB) overlaps the logits region: consumed by proj before QK writes logits
  f16*   Wf16   = (f16*)(ws + 3 * 16777216);

  // 0) preconvert weights to fp16
  wcvt_kernel<<<dim3(256, 3), 256, 0, stream>>>(Wq, Wk, Wv, Wf16);
  // 1) fused q/k/v projections -> fp16 (S,B,DH) flat
  proj_kernel<<<dim3(128, 4, 3), 256, 0, stream>>>(q, k, v, Wf16, bq, bk, bv,
                                                   qt, kt, vt);
  // 2) logits[b,d,e] = sum_s q_[b,d,s] k_[b,s,e]  (+mask -> -1e30), BM=64 -> 256 blocks
  gemm_tn_kernel<0, 2><<<dim3(4, 8, 8), 256, 0, stream>>>(
      qt, 1048576L, 2048, kt, 1048576L, 512, 2048, mask, logits, 262144L, 512);
  // 3) P = softmax(logits) over e, fp16
  softmax_kernel<<<dim3(1024), 256, 0, stream>>>(logits, P);
  // 4) out[b,d,s] = sum_e P[b,d,e] v_[b,e,s]  -> f32 d_out, BM=128 -> 512 blocks
  gemm_tn_kernel<1, 4><<<dim3(16, 4, 8), 256, 0, stream>>>(
      P, 262144L, 512, vt, 1048576L, 2048, 512, nullptr, (float*)d_out, 1048576L, 2048);
}

// Round 6
// 199.522 us; speedup vs baseline: 1.0182x; 1.0182x over previous
//
#include <hip/hip_runtime.h>
#include <stdint.h>

typedef _Float16 f16;
typedef __attribute__((ext_vector_type(8))) _Float16 f16x8;
typedef __attribute__((ext_vector_type(4))) float f32x4;
typedef __attribute__((ext_vector_type(2))) unsigned int u32x2;
typedef __attribute__((ext_vector_type(4))) unsigned int u32x4;
typedef decltype(__builtin_amdgcn_cvt_pkrtz(0.f, 0.f)) h2_t;

#define S_LEN 2048
#define BATCH 8
#define D_IN  1024
#define DHALF 512

__device__ __forceinline__ unsigned lds_off(const void* p) {
  return (unsigned)(size_t)p;
}

// async global->LDS DMA, 16B per lane. LDS dest is wave-uniform base (+lane*16 by HW).
__device__ __forceinline__ void dma16(const void* g, void* lds_uniform) {
  __builtin_amdgcn_global_load_lds(
      (const __attribute__((address_space(1))) void*)g,
      (__attribute__((address_space(3))) void*)lds_uniform, 16, 0, 0);
}

// ---------------------------------------------------------------------------
// W f32 -> f16 preconvert (one-shot, ~3MB): out[z] = (f16)W[z], layout [n][k].
// ---------------------------------------------------------------------------
__global__ __launch_bounds__(256) void wcvt_kernel(
    const float* __restrict__ Wq, const float* __restrict__ Wk, const float* __restrict__ Wv,
    f16* __restrict__ out)
{
  const int z = blockIdx.y;
  const float* W = (z == 0) ? Wq : (z == 1) ? Wk : Wv;
  const int idx = (blockIdx.x * 256 + threadIdx.x) * 8;
  f32x4 a = *(const f32x4*)(W + idx);
  f32x4 b = *(const f32x4*)(W + idx + 4);
  union { h2_t h2[4]; f16x8 v; } u;
  u.h2[0] = __builtin_amdgcn_cvt_pkrtz(a.x, a.y);
  u.h2[1] = __builtin_amdgcn_cvt_pkrtz(a.z, a.w);
  u.h2[2] = __builtin_amdgcn_cvt_pkrtz(b.x, b.y);
  u.h2[3] = __builtin_amdgcn_cvt_pkrtz(b.z, b.w);
  *(f16x8*)(out + (size_t)z * (DHALF * D_IN) + idx) = u.v;
}

// ---------------------------------------------------------------------------
// Projection: out[s,b,e] = sum_d X[s,b,d] * W[e,d] + bias[e], stored fp16.
// TRAFFIC-MINIMAL tiling: BM=128 x BN=512 (full width) -> A staged ONCE
// (192 MB compulsory vs 768 MB at BN=128). 512 threads / 8 waves,
// wave-tile 64x128 (acc[4][8]). global_load_lds DMA, triple-buffered,
// counted vmcnt(6) (T4): sets {k,k+1} in flight, never drain to 0.
// A staged f32 w/ src swizzle byte^=(row&7)<<4 (128B rows);
// B staged f16 w/ byte^=((row>>1)&3)<<4 (64B rows).
// ---------------------------------------------------------------------------
__global__ __launch_bounds__(512, 2) void proj_kernel(
    const float* __restrict__ Xq, const float* __restrict__ Xk, const float* __restrict__ Xv,
    const f16* __restrict__ Wf16,
    const float* __restrict__ bq, const float* __restrict__ bk, const float* __restrict__ bv,
    f16* __restrict__ oq, f16* __restrict__ ok, f16* __restrict__ ov)
{
  const int z = blockIdx.z;
  const float* X    = (z == 0) ? Xq : (z == 1) ? Xk : Xv;
  const f16*   W    = Wf16 + (size_t)z * (DHALF * D_IN);
  const float* bias = (z == 0) ? bq : (z == 1) ? bk : bv;
  f16* out          = (z == 0) ? oq : (z == 1) ? ok : ov;

  const int m0 = blockIdx.x * 128;
  const int tid = threadIdx.x;
  const int lane = tid & 63;
  const int wave = tid >> 6;          // 0..7
  const int wr = wave >> 2;           // 0..1  (row group, 64 rows)
  const int wc = wave & 3;            // 0..3  (col group, 128 cols)
  const int g = lane >> 4, rl = lane & 15;

  __shared__ float As[3][4096];       // 3 x 16KB: [128 rows][32 k f32], src-swizzled
  __shared__ f16   Bs[3][16384];      // 3 x 32KB: [512 rows][32 k f16], src-swizzled

  f32x4 acc[4][8];
#pragma unroll
  for (int i = 0; i < 4; i++)
#pragma unroll
    for (int j = 0; j < 8; j++) acc[i][j] = (f32x4){0.f, 0.f, 0.f, 0.f};

  // ---- DMA source/dest precompute (6 DMA per wave per set: 2 A + 4 B) ----
  const char* gaA[2];
  unsigned    ldA[2];
#pragma unroll
  for (int i = 0; i < 2; i++) {
    unsigned L   = wave * 2048 + i * 1024 + lane * 16;   // 0..16383
    unsigned row = L >> 7;                               // 0..127
    unsigned col = (L ^ ((row & 7) << 4)) & 127;
    gaA[i] = (const char*)X + (size_t)(m0 + row) * (D_IN * 4) + col;
    ldA[i] = wave * 2048 + i * 1024;
  }
  const char* gaB[4];
  unsigned    ldB[4];
#pragma unroll
  for (int i = 0; i < 4; i++) {
    unsigned L   = wave * 4096 + i * 1024 + lane * 16;   // 0..32767
    unsigned row = L >> 6;                               // 0..511
    unsigned col = (L ^ (((row >> 1) & 3) << 4)) & 63;
    gaB[i] = (const char*)W + (size_t)row * (D_IN * 2) + col;
    ldB[i] = wave * 4096 + i * 1024;
  }

#define ISSUE(BUF, KSTEP) {                                                   \
  char* abase = (char*)&As[0][0] + (unsigned)(BUF) * 16384u;                  \
  char* bbase = (char*)&Bs[0][0] + (unsigned)(BUF) * 32768u;                  \
  _Pragma("unroll")                                                           \
  for (int i = 0; i < 2; i++)                                                 \
    dma16(gaA[i] + (KSTEP) * 128, abase + ldA[i]);                            \
  _Pragma("unroll")                                                           \
  for (int i = 0; i < 4; i++)                                                 \
    dma16(gaB[i] + (KSTEP) * 64,  bbase + ldB[i]); }

#define PCOMPUTE(BUF) {                                                       \
  const char* abase = (const char*)&As[0][0] + (unsigned)(BUF) * 16384u;      \
  const char* bbase = (const char*)&Bs[0][0] + (unsigned)(BUF) * 32768u;      \
  f16x8 bf[8];                                                                \
  _Pragma("unroll")                                                           \
  for (int j = 0; j < 8; j++) {                                               \
    unsigned row = wc * 128 + j * 16 + rl;                                    \
    unsigned off = row * 64 + ((g * 16) ^ (((rl >> 1) & 3) << 4));            \
    bf[j] = *(const f16x8*)(bbase + off);                                     \
  }                                                                           \
  f16x8 af[4];                                                                \
  _Pragma("unroll")                                                           \
  for (int i = 0; i < 4; i++) {                                               \
    unsigned row = wr * 64 + i * 16 + rl;                                     \
    unsigned off = row * 128 + ((g * 32) ^ ((rl & 7) << 4));                  \
    f32x4 lo = *(const f32x4*)(abase + off);                                  \
    f32x4 hi = *(const f32x4*)(abase + (off ^ 16));                           \
    union { h2_t h2[4]; f16x8 v; } u;                                         \
    u.h2[0] = __builtin_amdgcn_cvt_pkrtz(lo.x, lo.y);                         \
    u.h2[1] = __builtin_amdgcn_cvt_pkrtz(lo.z, lo.w);                         \
    u.h2[2] = __builtin_amdgcn_cvt_pkrtz(hi.x, hi.y);                         \
    u.h2[3] = __builtin_amdgcn_cvt_pkrtz(hi.z, hi.w);                         \
    af[i] = u.v;                                                              \
  }                                                                           \
  _Pragma("unroll")                                                           \
  for (int i = 0; i < 4; i++)                                                 \
    _Pragma("unroll")                                                         \
    for (int j = 0; j < 8; j++)                                               \
      acc[i][j] = __builtin_amdgcn_mfma_f32_16x16x32_f16(af[i], bf[j], acc[i][j], 0, 0, 0); }

  // prologue: sets 0,1 in flight (12 DMA/wave)
  ISSUE(0, 0);
  ISSUE(1, 1);

  int cb = 0;   // compute buffer for step k
  int ib = 2;   // issue buffer for step k+2
  for (int k = 0; k < 32; ++k) {
    if (k < 31) { asm volatile("s_waitcnt vmcnt(6)" ::: "memory"); }  // set k done
    else        { asm volatile("s_waitcnt vmcnt(0)" ::: "memory"); }  // tail drain
    __builtin_amdgcn_s_barrier();
    __builtin_amdgcn_sched_barrier(0);
    if (k + 2 < 32) {
      ISSUE(ib, k + 2);                   // buf freed by compute(k-1)
      ib = (ib == 2) ? 0 : ib + 1;
    }
    PCOMPUTE(cb);
    cb = (cb == 2) ? 0 : cb + 1;
  }
#undef ISSUE
#undef PCOMPUTE

  // epilogue: + bias, cast fp16; C/D layout: col = lane&15, row = (lane>>4)*4 + r
#pragma unroll
  for (int i = 0; i < 4; i++) {
    const int row = m0 + wr * 64 + i * 16 + g * 4;
#pragma unroll
    for (int j = 0; j < 8; j++) {
      const int col = wc * 128 + j * 16 + rl;
      const float bb = bias[col];
#pragma unroll
      for (int r = 0; r < 4; r++)
        out[(size_t)(row + r) * DHALF + col] = (f16)(acc[i][j][r] + bb);
    }
  }
}

// ---------------------------------------------------------------------------
// Batched GEMM-TN: C[b] = A[b] (M x K, K-contig) * B[b] (K x N, N-contig).
// Template MI = M-fragments per wave (4 -> BM=128, 2 -> BM=64).
// B transpose-staged into [4k][16n] subtiles, phys order {0,2,4,6,1,3,5,7},
// read via ds_read_b64_tr_b16 (+offset:512).
// EPI=0: apply attn mask, store f32 logits.  EPI=1: store f32 to out.
// ---------------------------------------------------------------------------
template <int EPI, int MI>
__global__ __launch_bounds__(256, 3) void gemm_tn_kernel(
    const f16* __restrict__ A, long batchA, int lda,
    const f16* __restrict__ Bm, long batchB, int ldb,
    int Ksize,
    const int* __restrict__ mask,
    float* __restrict__ out, long batchOut, int ldo)
{
  constexpr int BM = MI * 32;            // block M-tile
  const int bz = blockIdx.z;
  const int n0 = blockIdx.x * 128;
  const int m0 = blockIdx.y * BM;
  const f16* Ab = A + (size_t)bz * batchA;
  const f16* Bb = Bm + (size_t)bz * batchB;

  const int tid = threadIdx.x, lane = tid & 63, wave = tid >> 6;
  const int wr = wave >> 1, wc = wave & 1;
  const int g = lane >> 4, rl = lane & 15;

  __shared__ f16 As[2][BM * 40];         // padded stride 40
  __shared__ f16 Bs[2][32 * 128];        // [n_blk(8)][phys(8)] blocks of [4][16]

  f32x4 acc[MI][4];
#pragma unroll
  for (int i = 0; i < MI; i++)
#pragma unroll
    for (int j = 0; j < 4; j++) acc[i][j] = (f32x4){0.f, 0.f, 0.f, 0.f};

  // A staging: BM*32 f16 by 256 threads
  const int arow = (MI == 4) ? (tid >> 1) : (tid >> 2);
  const int ah   = (MI == 4) ? ((tid & 1) * 16) : ((tid & 3) * 8);
  const int brow = tid >> 3;             // k-row 0..31
  const int bcol = (tid & 7) * 16;       // n offset
  const int sblk = brow >> 2;
  const int phys = ((sblk & 1) << 2) | (sblk >> 1);
  const int bwoff = ((tid & 7) * 8 + phys) * 128 + (brow & 3) * 32;  // bytes
  const f16* gA = Ab + (size_t)(m0 + arow) * lda + ah;
  const f16* gB = Bb + (size_t)brow * ldb + n0 + bcol;

  const unsigned bs_base = lds_off(&Bs[0][0]);

  f16x8 va0, va1, vb0, vb1;

#define GLOAD(K0)                                                       \
  va0 = *(const f16x8*)(gA + (K0));                                     \
  if (MI == 4) va1 = *(const f16x8*)(gA + (K0) + 8);                    \
  { const f16* gb = gB + (size_t)(K0) * ldb;                            \
    vb0 = *(const f16x8*)(gb);                                          \
    vb1 = *(const f16x8*)(gb + 8); }

#define GWRITE(BUF) {                                                   \
  *(f16x8*)&As[BUF][arow * 40 + ah] = va0;                              \
  if (MI == 4) *(f16x8*)&As[BUF][arow * 40 + ah + 8] = va1;             \
  char* wb = (char*)&Bs[BUF][0] + bwoff;                                \
  *(f16x8*)wb        = vb0;                                             \
  *(f16x8*)(wb + 16) = vb1; }

  GLOAD(0);
  GWRITE(0);
  __syncthreads();

  int cur = 0;
#pragma unroll 2
  for (int k0 = 0; k0 < Ksize; k0 += 32) {
    const bool more = (k0 + 32 < Ksize);
    if (more) { GLOAD(k0 + 32); }

    f16x8 af[MI];
#pragma unroll
    for (int i = 0; i < MI; i++)
      af[i] = *(const f16x8*)&As[cur][(wr * (MI * 16) + i * 16 + rl) * 40 + g * 8];

    f16x8 bf[4];
#pragma unroll
    for (int j = 0; j < 4; j++) {
      unsigned addr = bs_base + (unsigned)cur * 8192u +
                      (unsigned)((wc * 4 + j) * 1024) + (unsigned)lane * 8u;
      u32x2 lo, hi;
      asm volatile("ds_read_b64_tr_b16 %0, %1" : "=v"(lo) : "v"(addr));
      asm volatile("ds_read_b64_tr_b16 %0, %1 offset:512" : "=v"(hi) : "v"(addr));
      union { u32x4 u; f16x8 h; } cc;
      cc.u = (u32x4){lo.x, lo.y, hi.x, hi.y};
      bf[j] = cc.h;
    }
    // rule 18: fence tr-read results before register-only MFMA consumers
    asm volatile("s_waitcnt lgkmcnt(0)" ::: "memory");
    __builtin_amdgcn_sched_barrier(0);

#pragma unroll
    for (int i = 0; i < MI; i++)
#pragma unroll
      for (int j = 0; j < 4; j++)
        acc[i][j] = __builtin_amdgcn_mfma_f32_16x16x32_f16(af[i], bf[j], acc[i][j], 0, 0, 0);

    if (more) {
      GWRITE(cur ^ 1);
      __syncthreads();
      cur ^= 1;
    }
  }
#undef GLOAD
#undef GWRITE

  float* ob = out + (size_t)bz * batchOut;
#pragma unroll
  for (int i = 0; i < MI; i++) {
    const int row = m0 + wr * (MI * 16) + i * 16 + g * 4;
#pragma unroll
    for (int j = 0; j < 4; j++) {
      const int col = n0 + wc * 64 + j * 16 + rl;
#pragma unroll
      for (int r = 0; r < 4; r++) {
        float val = acc[i][j][r];
        if (EPI == 0) {
          if (mask[(row + r) * DHALF + col] != 0) val = -1e30f;
        }
        ob[(size_t)(row + r) * ldo + col] = val;
      }
    }
  }
}

// ---------------------------------------------------------------------------
// Row softmax over e (512) for 4096 rows; one wave per row; fp16 output.
// ---------------------------------------------------------------------------
__global__ __launch_bounds__(256) void softmax_kernel(
    const float* __restrict__ logits, f16* __restrict__ P)
{
  const int row  = blockIdx.x * 4 + (threadIdx.x >> 6);
  const int lane = threadIdx.x & 63;
  const float* rp = logits + (size_t)row * DHALF + lane * 8;
  f32x4 x0 = *(const f32x4*)rp;
  f32x4 x1 = *(const f32x4*)(rp + 4);

  float m = fmaxf(fmaxf(fmaxf(x0.x, x0.y), fmaxf(x0.z, x0.w)),
                  fmaxf(fmaxf(x1.x, x1.y), fmaxf(x1.z, x1.w)));
#pragma unroll
  for (int off = 32; off > 0; off >>= 1) m = fmaxf(m, __shfl_xor(m, off, 64));

  float e0 = __expf(x0.x - m), e1 = __expf(x0.y - m);
  float e2 = __expf(x0.z - m), e3 = __expf(x0.w - m);
  float e4 = __expf(x1.x - m), e5 = __expf(x1.y - m);
  float e6 = __expf(x1.z - m), e7 = __expf(x1.w - m);
  float s = ((e0 + e1) + (e2 + e3)) + ((e4 + e5) + (e6 + e7));
#pragma unroll
  for (int off = 32; off > 0; off >>= 1) s += __shfl_xor(s, off, 64);
  const float inv = 1.0f / s;

  union { h2_t h2[4]; f16x8 v; } o;
  o.h2[0] = __builtin_amdgcn_cvt_pkrtz(e0 * inv, e1 * inv);
  o.h2[1] = __builtin_amdgcn_cvt_pkrtz(e2 * inv, e3 * inv);
  o.h2[2] = __builtin_amdgcn_cvt_pkrtz(e4 * inv, e5 * inv);
  o.h2[3] = __builtin_amdgcn_cvt_pkrtz(e6 * inv, e7 * inv);
  *(f16x8*)(P + (size_t)row * DHALF + lane * 8) = o.v;
}

// ---------------------------------------------------------------------------
extern "C" void kernel_launch(void* const* d_in, const int* in_sizes, int n_in,
                              void* d_out, int out_size, void* d_ws, size_t ws_size,
                              hipStream_t stream) {
  const float* q    = (const float*)d_in[0];
  const float* k    = (const float*)d_in[1];
  const float* v    = (const float*)d_in[2];
  const int*   mask = (const int*)d_in[3];
  const float* Wq   = (const float*)d_in[4];
  const float* bq   = (const float*)d_in[5];
  const float* Wk   = (const float*)d_in[6];
  const float* bk   = (const float*)d_in[7];
  const float* Wv   = (const float*)d_in[8];
  const float* bv   = (const float*)d_in[9];

  char* ws = (char*)d_ws;
  f16*   qt     = (f16*)(ws);                                  // 16 MB
  f16*   kt     = (f16*)(ws + 16777216);                       // 16 MB
  f16*   vt     = (f16*)(ws + 2 * 16777216);                   // 16 MB
  float* logits = (float*)(ws + 3 * 16777216);                 // 8 MB
  f16*   P      = (f16*)(ws + 3 * 16777216 + 8388608);         // 4 MB
  // Wf16 (3 MB) overlaps the logits region: consumed by proj before QK writes logits
  f16*   Wf16   = (f16*)(ws + 3 * 16777216);

  // 0) preconvert weights to fp16
  wcvt_kernel<<<dim3(256, 3), 256, 0, stream>>>(Wq, Wk, Wv, Wf16);
  // 1) fused q/k/v projections -> fp16 (S,B,DH) flat; BN=512 -> A read once
  proj_kernel<<<dim3(128, 1, 3), 512, 0, stream>>>(q, k, v, Wf16, bq, bk, bv,
                                                   qt, kt, vt);
  // 2) logits[b,d,e] = sum_s q_[b,d,s] k_[b,s,e]  (+mask -> -1e30), BM=64 -> 256 blocks
  gemm_tn_kernel<0, 2><<<dim3(4, 8, 8), 256, 0, stream>>>(
      qt, 1048576L, 2048, kt, 1048576L, 512, 2048, mask, logits, 262144L, 512);
  // 3) P = softmax(logits) over e, fp16
  softmax_kernel<<<dim3(1024), 256, 0, stream>>>(logits, P);
  // 4) out[b,d,s] = sum_e P[b,d,e] v_[b,e,s]  -> f32 d_out, BM=128 -> 512 blocks
  gemm_tn_kernel<1, 4><<<dim3(16, 4, 8), 256, 0, stream>>>(
      P, 262144L, 512, vt, 1048576L, 2048, 512, nullptr, (float*)d_out, 1048576L, 2048);
}

// Round 7
// 196.940 us; speedup vs baseline: 1.0315x; 1.0131x over previous
//
#include <hip/hip_runtime.h>
#include <stdint.h>

typedef _Float16 f16;
typedef __attribute__((ext_vector_type(8))) _Float16 f16x8;
typedef __attribute__((ext_vector_type(4))) float f32x4;
typedef __attribute__((ext_vector_type(2))) unsigned int u32x2;
typedef __attribute__((ext_vector_type(4))) unsigned int u32x4;
typedef decltype(__builtin_amdgcn_cvt_pkrtz(0.f, 0.f)) h2_t;

#define S_LEN 2048
#define BATCH 8
#define D_IN  1024
#define DHALF 512

__device__ __forceinline__ unsigned lds_off(const void* p) {
  return (unsigned)(size_t)p;
}

// async global->LDS DMA, 16B per lane. LDS dest is wave-uniform base (+lane*16 by HW).
// AUX: CPol bits, gfx950: sc0=1, nt=2, sc1=16. NT for single-use streams keeps
// them from evicting reused data (W) out of the per-XCD L2.
template <int AUX>
__device__ __forceinline__ void dma16(const void* g, void* lds_uniform) {
  __builtin_amdgcn_global_load_lds(
      (const __attribute__((address_space(1))) void*)g,
      (__attribute__((address_space(3))) void*)lds_uniform, 16, 0, AUX);
}

// ---------------------------------------------------------------------------
// W f32 -> f16 preconvert (one-shot, ~3MB): out[z] = (f16)W[z], layout [n][k].
// ---------------------------------------------------------------------------
__global__ __launch_bounds__(256) void wcvt_kernel(
    const float* __restrict__ Wq, const float* __restrict__ Wk, const float* __restrict__ Wv,
    f16* __restrict__ out)
{
  const int z = blockIdx.y;
  const float* W = (z == 0) ? Wq : (z == 1) ? Wk : Wv;
  const int idx = (blockIdx.x * 256 + threadIdx.x) * 8;
  f32x4 a = *(const f32x4*)(W + idx);
  f32x4 b = *(const f32x4*)(W + idx + 4);
  union { h2_t h2[4]; f16x8 v; } u;
  u.h2[0] = __builtin_amdgcn_cvt_pkrtz(a.x, a.y);
  u.h2[1] = __builtin_amdgcn_cvt_pkrtz(a.z, a.w);
  u.h2[2] = __builtin_amdgcn_cvt_pkrtz(b.x, b.y);
  u.h2[3] = __builtin_amdgcn_cvt_pkrtz(b.z, b.w);
  *(f16x8*)(out + (size_t)z * (DHALF * D_IN) + idx) = u.v;
}

// ---------------------------------------------------------------------------
// Projection: out[s,b,e] = sum_d X[s,b,d] * W[e,d] + bias[e], stored fp16.
// BM=128 x BN=512 (A staged once). 512 thr / 8 waves, wave-tile 64x128.
// global_load_lds DMA, triple-buffered, counted vmcnt(6).
// A (single-use f32 stream) staged with NT cache policy -> does not evict
// W from L2; B (W fp16, 3MB total across z) stays L2-resident.
// A src swizzle byte^=(row&7)<<4; B src swizzle byte^=((row>>1)&3)<<4.
// ---------------------------------------------------------------------------
__global__ __launch_bounds__(512, 2) void proj_kernel(
    const float* __restrict__ Xq, const float* __restrict__ Xk, const float* __restrict__ Xv,
    const f16* __restrict__ Wf16,
    const float* __restrict__ bq, const float* __restrict__ bk, const float* __restrict__ bv,
    f16* __restrict__ oq, f16* __restrict__ ok, f16* __restrict__ ov)
{
  const int z = blockIdx.z;
  const float* X    = (z == 0) ? Xq : (z == 1) ? Xk : Xv;
  const f16*   W    = Wf16 + (size_t)z * (DHALF * D_IN);
  const float* bias = (z == 0) ? bq : (z == 1) ? bk : bv;
  f16* out          = (z == 0) ? oq : (z == 1) ? ok : ov;

  const int m0 = blockIdx.x * 128;
  const int tid = threadIdx.x;
  const int lane = tid & 63;
  const int wave = tid >> 6;          // 0..7
  const int wr = wave >> 2;           // 0..1  (row group, 64 rows)
  const int wc = wave & 3;            // 0..3  (col group, 128 cols)
  const int g = lane >> 4, rl = lane & 15;

  __shared__ float As[3][4096];       // 3 x 16KB: [128 rows][32 k f32], src-swizzled
  __shared__ f16   Bs[3][16384];      // 3 x 32KB: [512 rows][32 k f16], src-swizzled

  f32x4 acc[4][8];
#pragma unroll
  for (int i = 0; i < 4; i++)
#pragma unroll
    for (int j = 0; j < 8; j++) acc[i][j] = (f32x4){0.f, 0.f, 0.f, 0.f};

  // ---- DMA source/dest precompute (6 DMA per wave per set: 2 A + 4 B) ----
  const char* gaA[2];
  unsigned    ldA[2];
#pragma unroll
  for (int i = 0; i < 2; i++) {
    unsigned L   = wave * 2048 + i * 1024 + lane * 16;   // 0..16383
    unsigned row = L >> 7;                               // 0..127
    unsigned col = (L ^ ((row & 7) << 4)) & 127;
    gaA[i] = (const char*)X + (size_t)(m0 + row) * (D_IN * 4) + col;
    ldA[i] = wave * 2048 + i * 1024;
  }
  const char* gaB[4];
  unsigned    ldB[4];
#pragma unroll
  for (int i = 0; i < 4; i++) {
    unsigned L   = wave * 4096 + i * 1024 + lane * 16;   // 0..32767
    unsigned row = L >> 6;                               // 0..511
    unsigned col = (L ^ (((row >> 1) & 3) << 4)) & 63;
    gaB[i] = (const char*)W + (size_t)row * (D_IN * 2) + col;
    ldB[i] = wave * 4096 + i * 1024;
  }

#define ISSUE(BUF, KSTEP) {                                                   \
  char* abase = (char*)&As[0][0] + (unsigned)(BUF) * 16384u;                  \
  char* bbase = (char*)&Bs[0][0] + (unsigned)(BUF) * 32768u;                  \
  _Pragma("unroll")                                                           \
  for (int i = 0; i < 2; i++)                                                 \
    dma16<2>(gaA[i] + (KSTEP) * 128, abase + ldA[i]);   /* NT: stream A */    \
  _Pragma("unroll")                                                           \
  for (int i = 0; i < 4; i++)                                                 \
    dma16<0>(gaB[i] + (KSTEP) * 64,  bbase + ldB[i]); } /* B: L2-cached */

#define PCOMPUTE(BUF) {                                                       \
  const char* abase = (const char*)&As[0][0] + (unsigned)(BUF) * 16384u;      \
  const char* bbase = (const char*)&Bs[0][0] + (unsigned)(BUF) * 32768u;      \
  f16x8 bf[8];                                                                \
  _Pragma("unroll")                                                           \
  for (int j = 0; j < 8; j++) {                                               \
    unsigned row = wc * 128 + j * 16 + rl;                                    \
    unsigned off = row * 64 + ((g * 16) ^ (((rl >> 1) & 3) << 4));            \
    bf[j] = *(const f16x8*)(bbase + off);                                     \
  }                                                                           \
  f16x8 af[4];                                                                \
  _Pragma("unroll")                                                           \
  for (int i = 0; i < 4; i++) {                                               \
    unsigned row = wr * 64 + i * 16 + rl;                                     \
    unsigned off = row * 128 + ((g * 32) ^ ((rl & 7) << 4));                  \
    f32x4 lo = *(const f32x4*)(abase + off);                                  \
    f32x4 hi = *(const f32x4*)(abase + (off ^ 16));                           \
    union { h2_t h2[4]; f16x8 v; } u;                                         \
    u.h2[0] = __builtin_amdgcn_cvt_pkrtz(lo.x, lo.y);                         \
    u.h2[1] = __builtin_amdgcn_cvt_pkrtz(lo.z, lo.w);                         \
    u.h2[2] = __builtin_amdgcn_cvt_pkrtz(hi.x, hi.y);                         \
    u.h2[3] = __builtin_amdgcn_cvt_pkrtz(hi.z, hi.w);                         \
    af[i] = u.v;                                                              \
  }                                                                           \
  _Pragma("unroll")                                                           \
  for (int i = 0; i < 4; i++)                                                 \
    _Pragma("unroll")                                                         \
    for (int j = 0; j < 8; j++)                                               \
      acc[i][j] = __builtin_amdgcn_mfma_f32_16x16x32_f16(af[i], bf[j], acc[i][j], 0, 0, 0); }

  // prologue: sets 0,1 in flight (12 DMA/wave)
  ISSUE(0, 0);
  ISSUE(1, 1);

  int cb = 0;   // compute buffer for step k
  int ib = 2;   // issue buffer for step k+2
  for (int k = 0; k < 32; ++k) {
    if (k < 31) { asm volatile("s_waitcnt vmcnt(6)" ::: "memory"); }  // set k done
    else        { asm volatile("s_waitcnt vmcnt(0)" ::: "memory"); }  // tail drain
    __builtin_amdgcn_s_barrier();
    __builtin_amdgcn_sched_barrier(0);
    if (k + 2 < 32) {
      ISSUE(ib, k + 2);                   // buf freed by compute(k-1)
      ib = (ib == 2) ? 0 : ib + 1;
    }
    PCOMPUTE(cb);
    cb = (cb == 2) ? 0 : cb + 1;
  }
#undef ISSUE
#undef PCOMPUTE

  // epilogue: + bias, cast fp16; C/D layout: col = lane&15, row = (lane>>4)*4 + r
#pragma unroll
  for (int i = 0; i < 4; i++) {
    const int row = m0 + wr * 64 + i * 16 + g * 4;
#pragma unroll
    for (int j = 0; j < 8; j++) {
      const int col = wc * 128 + j * 16 + rl;
      const float bb = bias[col];
#pragma unroll
      for (int r = 0; r < 4; r++)
        out[(size_t)(row + r) * DHALF + col] = (f16)(acc[i][j][r] + bb);
    }
  }
}

// ---------------------------------------------------------------------------
// Batched GEMM-TN: C[b] = A[b] (M x K, K-contig) * B[b] (K x N, N-contig).
// Template MI = M-fragments per wave (4 -> BM=128, 2 -> BM=64).
// B transpose-staged into [4k][16n] subtiles, phys order {0,2,4,6,1,3,5,7},
// read via ds_read_b64_tr_b16 (+offset:512).
// EPI=0: apply attn mask, store f32 logits.  EPI=1: store f32 to out.
// ---------------------------------------------------------------------------
template <int EPI, int MI>
__global__ __launch_bounds__(256, 3) void gemm_tn_kernel(
    const f16* __restrict__ A, long batchA, int lda,
    const f16* __restrict__ Bm, long batchB, int ldb,
    int Ksize,
    const int* __restrict__ mask,
    float* __restrict__ out, long batchOut, int ldo)
{
  constexpr int BM = MI * 32;            // block M-tile
  const int bz = blockIdx.z;
  const int n0 = blockIdx.x * 128;
  const int m0 = blockIdx.y * BM;
  const f16* Ab = A + (size_t)bz * batchA;
  const f16* Bb = Bm + (size_t)bz * batchB;

  const int tid = threadIdx.x, lane = tid & 63, wave = tid >> 6;
  const int wr = wave >> 1, wc = wave & 1;
  const int g = lane >> 4, rl = lane & 15;

  __shared__ f16 As[2][BM * 40];         // padded stride 40
  __shared__ f16 Bs[2][32 * 128];        // [n_blk(8)][phys(8)] blocks of [4][16]

  f32x4 acc[MI][4];
#pragma unroll
  for (int i = 0; i < MI; i++)
#pragma unroll
    for (int j = 0; j < 4; j++) acc[i][j] = (f32x4){0.f, 0.f, 0.f, 0.f};

  // A staging: BM*32 f16 by 256 threads
  const int arow = (MI == 4) ? (tid >> 1) : (tid >> 2);
  const int ah   = (MI == 4) ? ((tid & 1) * 16) : ((tid & 3) * 8);
  const int brow = tid >> 3;             // k-row 0..31
  const int bcol = (tid & 7) * 16;       // n offset
  const int sblk = brow >> 2;
  const int phys = ((sblk & 1) << 2) | (sblk >> 1);
  const int bwoff = ((tid & 7) * 8 + phys) * 128 + (brow & 3) * 32;  // bytes
  const f16* gA = Ab + (size_t)(m0 + arow) * lda + ah;
  const f16* gB = Bb + (size_t)brow * ldb + n0 + bcol;

  const unsigned bs_base = lds_off(&Bs[0][0]);

  f16x8 va0, va1, vb0, vb1;

#define GLOAD(K0)                                                       \
  va0 = *(const f16x8*)(gA + (K0));                                     \
  if (MI == 4) va1 = *(const f16x8*)(gA + (K0) + 8);                    \
  { const f16* gb = gB + (size_t)(K0) * ldb;                            \
    vb0 = *(const f16x8*)(gb);                                          \
    vb1 = *(const f16x8*)(gb + 8); }

#define GWRITE(BUF) {                                                   \
  *(f16x8*)&As[BUF][arow * 40 + ah] = va0;                              \
  if (MI == 4) *(f16x8*)&As[BUF][arow * 40 + ah + 8] = va1;             \
  char* wb = (char*)&Bs[BUF][0] + bwoff;                                \
  *(f16x8*)wb        = vb0;                                             \
  *(f16x8*)(wb + 16) = vb1; }

  GLOAD(0);
  GWRITE(0);
  __syncthreads();

  int cur = 0;
#pragma unroll 2
  for (int k0 = 0; k0 < Ksize; k0 += 32) {
    const bool more = (k0 + 32 < Ksize);
    if (more) { GLOAD(k0 + 32); }

    f16x8 af[MI];
#pragma unroll
    for (int i = 0; i < MI; i++)
      af[i] = *(const f16x8*)&As[cur][(wr * (MI * 16) + i * 16 + rl) * 40 + g * 8];

    f16x8 bf[4];
#pragma unroll
    for (int j = 0; j < 4; j++) {
      unsigned addr = bs_base + (unsigned)cur * 8192u +
                      (unsigned)((wc * 4 + j) * 1024) + (unsigned)lane * 8u;
      u32x2 lo, hi;
      asm volatile("ds_read_b64_tr_b16 %0, %1" : "=v"(lo) : "v"(addr));
      asm volatile("ds_read_b64_tr_b16 %0, %1 offset:512" : "=v"(hi) : "v"(addr));
      union { u32x4 u; f16x8 h; } cc;
      cc.u = (u32x4){lo.x, lo.y, hi.x, hi.y};
      bf[j] = cc.h;
    }
    // rule 18: fence tr-read results before register-only MFMA consumers
    asm volatile("s_waitcnt lgkmcnt(0)" ::: "memory");
    __builtin_amdgcn_sched_barrier(0);

#pragma unroll
    for (int i = 0; i < MI; i++)
#pragma unroll
      for (int j = 0; j < 4; j++)
        acc[i][j] = __builtin_amdgcn_mfma_f32_16x16x32_f16(af[i], bf[j], acc[i][j], 0, 0, 0);

    if (more) {
      GWRITE(cur ^ 1);
      __syncthreads();
      cur ^= 1;
    }
  }
#undef GLOAD
#undef GWRITE

  float* ob = out + (size_t)bz * batchOut;
#pragma unroll
  for (int i = 0; i < MI; i++) {
    const int row = m0 + wr * (MI * 16) + i * 16 + g * 4;
#pragma unroll
    for (int j = 0; j < 4; j++) {
      const int col = n0 + wc * 64 + j * 16 + rl;
#pragma unroll
      for (int r = 0; r < 4; r++) {
        float val = acc[i][j][r];
        if (EPI == 0) {
          if (mask[(row + r) * DHALF + col] != 0) val = -1e30f;
        }
        ob[(size_t)(row + r) * ldo + col] = val;
      }
    }
  }
}

// ---------------------------------------------------------------------------
// Row softmax over e (512) for 4096 rows; one wave per row; fp16 output.
// ---------------------------------------------------------------------------
__global__ __launch_bounds__(256) void softmax_kernel(
    const float* __restrict__ logits, f16* __restrict__ P)
{
  const int row  = blockIdx.x * 4 + (threadIdx.x >> 6);
  const int lane = threadIdx.x & 63;
  const float* rp = logits + (size_t)row * DHALF + lane * 8;
  f32x4 x0 = *(const f32x4*)rp;
  f32x4 x1 = *(const f32x4*)(rp + 4);

  float m = fmaxf(fmaxf(fmaxf(x0.x, x0.y), fmaxf(x0.z, x0.w)),
                  fmaxf(fmaxf(x1.x, x1.y), fmaxf(x1.z, x1.w)));
#pragma unroll
  for (int off = 32; off > 0; off >>= 1) m = fmaxf(m, __shfl_xor(m, off, 64));

  float e0 = __expf(x0.x - m), e1 = __expf(x0.y - m);
  float e2 = __expf(x0.z - m), e3 = __expf(x0.w - m);
  float e4 = __expf(x1.x - m), e5 = __expf(x1.y - m);
  float e6 = __expf(x1.z - m), e7 = __expf(x1.w - m);
  float s = ((e0 + e1) + (e2 + e3)) + ((e4 + e5) + (e6 + e7));
#pragma unroll
  for (int off = 32; off > 0; off >>= 1) s += __shfl_xor(s, off, 64);
  const float inv = 1.0f / s;

  union { h2_t h2[4]; f16x8 v; } o;
  o.h2[0] = __builtin_amdgcn_cvt_pkrtz(e0 * inv, e1 * inv);
  o.h2[1] = __builtin_amdgcn_cvt_pkrtz(e2 * inv, e3 * inv);
  o.h2[2] = __builtin_amdgcn_cvt_pkrtz(e4 * inv, e5 * inv);
  o.h2[3] = __builtin_amdgcn_cvt_pkrtz(e6 * inv, e7 * inv);
  *(f16x8*)(P + (size_t)row * DHALF + lane * 8) = o.v;
}

// ---------------------------------------------------------------------------
extern "C" void kernel_launch(void* const* d_in, const int* in_sizes, int n_in,
                              void* d_out, int out_size, void* d_ws, size_t ws_size,
                              hipStream_t stream) {
  const float* q    = (const float*)d_in[0];
  const float* k    = (const float*)d_in[1];
  const float* v    = (const float*)d_in[2];
  const int*   mask = (const int*)d_in[3];
  const float* Wq   = (const float*)d_in[4];
  const float* bq   = (const float*)d_in[5];
  const float* Wk   = (const float*)d_in[6];
  const float* bk   = (const float*)d_in[7];
  const float* Wv   = (const float*)d_in[8];
  const float* bv   = (const float*)d_in[9];

  char* ws = (char*)d_ws;
  f16*   qt     = (f16*)(ws);                                  // 16 MB
  f16*   kt     = (f16*)(ws + 16777216);                       // 16 MB
  f16*   vt     = (f16*)(ws + 2 * 16777216);                   // 16 MB
  float* logits = (float*)(ws + 3 * 16777216);                 // 8 MB
  f16*   P      = (f16*)(ws + 3 * 16777216 + 8388608);         // 4 MB
  // Wf16 (3 MB) overlaps the logits region: consumed by proj before QK writes logits
  f16*   Wf16   = (f16*)(ws + 3 * 16777216);

  // 0) preconvert weights to fp16
  wcvt_kernel<<<dim3(256, 3), 256, 0, stream>>>(Wq, Wk, Wv, Wf16);
  // 1) fused q/k/v projections -> fp16 (S,B,DH) flat; BN=512 -> A read once
  proj_kernel<<<dim3(128, 1, 3), 512, 0, stream>>>(q, k, v, Wf16, bq, bk, bv,
                                                   qt, kt, vt);
  // 2) logits[b,d,e] = sum_s q_[b,d,s] k_[b,s,e]  (+mask -> -1e30), BM=64 -> 256 blocks
  gemm_tn_kernel<0, 2><<<dim3(4, 8, 8), 256, 0, stream>>>(
      qt, 1048576L, 2048, kt, 1048576L, 512, 2048, mask, logits, 262144L, 512);
  // 3) P = softmax(logits) over e, fp16
  softmax_kernel<<<dim3(1024), 256, 0, stream>>>(logits, P);
  // 4) out[b,d,s] = sum_e P[b,d,e] v_[b,e,s]  -> f32 d_out, BM=128 -> 512 blocks
  gemm_tn_kernel<1, 4><<<dim3(16, 4, 8), 256, 0, stream>>>(
      P, 262144L, 512, vt, 1048576L, 2048, 512, nullptr, (float*)d_out, 1048576L, 2048);
}

// Round 8
// 187.421 us; speedup vs baseline: 1.0839x; 1.0508x over previous
//
#include <hip/hip_runtime.h>
#include <stdint.h>

typedef _Float16 f16;
typedef __attribute__((ext_vector_type(8))) _Float16 f16x8;
typedef __attribute__((ext_vector_type(4))) float f32x4;
typedef __attribute__((ext_vector_type(2))) unsigned int u32x2;
typedef __attribute__((ext_vector_type(4))) unsigned int u32x4;
typedef decltype(__builtin_amdgcn_cvt_pkrtz(0.f, 0.f)) h2_t;

#define S_LEN 2048
#define BATCH 8
#define D_IN  1024
#define DHALF 512

__device__ __forceinline__ unsigned lds_off(const void* p) {
  return (unsigned)(size_t)p;
}

// ---------------------------------------------------------------------------
// W f32 -> f16 preconvert (one-shot, ~3MB): out[z] = (f16)W[z], layout [n][k].
// ---------------------------------------------------------------------------
__global__ __launch_bounds__(256) void wcvt_kernel(
    const float* __restrict__ Wq, const float* __restrict__ Wk, const float* __restrict__ Wv,
    f16* __restrict__ out)
{
  const int z = blockIdx.y;
  const float* W = (z == 0) ? Wq : (z == 1) ? Wk : Wv;
  const int idx = (blockIdx.x * 256 + threadIdx.x) * 8;
  f32x4 a = *(const f32x4*)(W + idx);
  f32x4 b = *(const f32x4*)(W + idx + 4);
  union { h2_t h2[4]; f16x8 v; } u;
  u.h2[0] = __builtin_amdgcn_cvt_pkrtz(a.x, a.y);
  u.h2[1] = __builtin_amdgcn_cvt_pkrtz(a.z, a.w);
  u.h2[2] = __builtin_amdgcn_cvt_pkrtz(b.x, b.y);
  u.h2[3] = __builtin_amdgcn_cvt_pkrtz(b.z, b.w);
  *(f16x8*)(out + (size_t)z * (DHALF * D_IN) + idx) = u.v;
}

// ---------------------------------------------------------------------------
// Projection v2 — DRAM-friendly A streaming.
// out[s,b,e] = sum_d X[s,b,d] * W[e,d] + bias[e], fp16.
// BM=128, BN=512 (2 n-halves of 256), K-chunk=128 (8 chunks).
// A read ONCE chip-wide in 512B-contiguous runs (32 lanes x 16B per row),
// nontemporal, reg-staged -> cvt f16 -> XOR-swizzled LDS [row][128k]
// (byte ^= (row&7)<<4; write b64 / read b128, ~2-way free).
// B (W fp16, L2-resident) reg-staged per n-half into same-layout LDS.
// A dbuf 2x32KB + B 64KB = 128KB. Raw s_barrier + lgkmcnt only -- no
// __syncthreads() vmcnt(0) drain of in-flight prefetches.
// Per kc: writeA, bar, writeB(n0), bar, [issue B(n1)] compute(n0),
//         bar, writeB(n1), [issue A/B(kc+1)], bar, compute(n1).
// ---------------------------------------------------------------------------
__global__ __launch_bounds__(512, 1) void proj_kernel(
    const float* __restrict__ Xq, const float* __restrict__ Xk, const float* __restrict__ Xv,
    const f16* __restrict__ Wf16,
    const float* __restrict__ bq, const float* __restrict__ bk, const float* __restrict__ bv,
    f16* __restrict__ oq, f16* __restrict__ ok, f16* __restrict__ ov)
{
  const int z = blockIdx.z;
  const float* X    = (z == 0) ? Xq : (z == 1) ? Xk : Xv;
  const f16*   W    = Wf16 + (size_t)z * (DHALF * D_IN);
  const float* bias = (z == 0) ? bq : (z == 1) ? bk : bv;
  f16* out          = (z == 0) ? oq : (z == 1) ? ok : ov;

  const int m0 = blockIdx.x * 128;
  const int tid = threadIdx.x;
  const int lane = tid & 63;
  const int wave = tid >> 6;          // 0..7
  const int rl = lane & 15, g = lane >> 4;

  __shared__ char Ab[2][32768];       // [128 rows][128 k] f16, swizzled
  __shared__ char Bb[65536];          // [256 nrows][128 k] f16, swizzled

  f32x4 acc[8][4];                    // [m-frag][h*2+nf]
#pragma unroll
  for (int i = 0; i < 8; i++)
#pragma unroll
    for (int j = 0; j < 4; j++) acc[i][j] = (f32x4){0.f, 0.f, 0.f, 0.f};

  // ---- A staging geometry: instr i covers rows wave*16 + i*2 + (lane>>5),
  //      512B run per row (32 lanes x 16B)
  const int arow_i = wave * 16 + (lane >> 5);          // + i*2
  const unsigned akoff = (lane & 31) * 16;             // byte within 512B run
  const char* gA = (const char*)X + (size_t)(m0 + arow_i) * (D_IN * 4) + akoff;
  // LDS write coords
  const unsigned aw_byte = ((lane & 31) * 8);          // f16 bytes, pre-swizzle

  // ---- B staging geometry: instr i covers nrows wave*32 + i*4 + (lane>>4),
  //      256B run per row (16 lanes x 16B)
  const int brow_i = wave * 32 + (lane >> 4);          // + i*4
  const unsigned bkoff = rl * 16;
  const char* gB = (const char*)W + (size_t)brow_i * (D_IN * 2) + bkoff;

  f32x4 aS[8];
  f16x8 bS[8];

#define ISSUE_A(KC) {                                                         \
  _Pragma("unroll")                                                           \
  for (int i = 0; i < 8; i++)                                                 \
    aS[i] = __builtin_nontemporal_load(                                       \
        (const f32x4*)(gA + (size_t)i * 2 * (D_IN * 4) + (KC) * 512)); }

#define ISSUE_B(KC, NH) {                                                     \
  _Pragma("unroll")                                                           \
  for (int i = 0; i < 8; i++)                                                 \
    bS[i] = *(const f16x8*)(gB + (size_t)((NH) * 256 + i * 4) * (D_IN * 2) +  \
                            (KC) * 256); }

#define WRITE_A(CUR) {                                                        \
  _Pragma("unroll")                                                           \
  for (int i = 0; i < 8; i++) {                                               \
    int row = arow_i + i * 2;                                                 \
    unsigned byte = aw_byte ^ ((unsigned)(row & 7) << 4);                     \
    union { h2_t h[2]; u32x2 u; } d;                                          \
    d.h[0] = __builtin_amdgcn_cvt_pkrtz(aS[i].x, aS[i].y);                    \
    d.h[1] = __builtin_amdgcn_cvt_pkrtz(aS[i].z, aS[i].w);                    \
    *(u32x2*)(&Ab[CUR][0] + (unsigned)row * 256 + byte) = d.u;                \
  } }

#define WRITE_B() {                                                           \
  _Pragma("unroll")                                                           \
  for (int i = 0; i < 8; i++) {                                               \
    int nrow = brow_i + i * 4;                                                \
    unsigned byte = bkoff ^ ((unsigned)(nrow & 7) << 4);                      \
    *(f16x8*)(&Bb[0] + (unsigned)nrow * 256 + byte) = bS[i];                  \
  } }

// compute one n-half: 4 k-steps x (8 af reads + 2 bf reads + 16 MFMA)
#define COMPUTE(CUR, H) {                                                     \
  _Pragma("unroll")                                                           \
  for (int ks = 0; ks < 4; ks++) {                                            \
    f16x8 af[8];                                                              \
    _Pragma("unroll")                                                         \
    for (int m = 0; m < 8; m++) {                                             \
      int row = m * 16 + rl;                                                  \
      unsigned byte = ((unsigned)(ks * 64 + g * 16)) ^                        \
                      ((unsigned)(row & 7) << 4);                             \
      af[m] = *(const f16x8*)(&Ab[CUR][0] + (unsigned)row * 256 + byte);      \
    }                                                                         \
    f16x8 bf[2];                                                              \
    _Pragma("unroll")                                                         \
    for (int nf = 0; nf < 2; nf++) {                                          \
      int nrow = wave * 32 + nf * 16 + rl;                                    \
      unsigned byte = ((unsigned)(ks * 64 + g * 16)) ^                        \
                      ((unsigned)(nrow & 7) << 4);                            \
      bf[nf] = *(const f16x8*)(&Bb[0] + (unsigned)nrow * 256 + byte);         \
    }                                                                         \
    _Pragma("unroll")                                                         \
    for (int m = 0; m < 8; m++)                                               \
      _Pragma("unroll")                                                       \
      for (int nf = 0; nf < 2; nf++)                                          \
        acc[m][(H) * 2 + nf] = __builtin_amdgcn_mfma_f32_16x16x32_f16(        \
            af[m], bf[nf], acc[m][(H) * 2 + nf], 0, 0, 0);                    \
  } }

#define LBAR  { asm volatile("s_waitcnt lgkmcnt(0)" ::: "memory");            \
                __builtin_amdgcn_s_barrier(); }

  // prologue: A(0), B(0,n0) in flight
  ISSUE_A(0);
  ISSUE_B(0, 0);

  int cur = 0;
  for (int kc = 0; kc < 8; ++kc) {
    WRITE_A(cur);            // compiler waits the A reg-loads (SSA)
    LBAR;                    // prev readers done; A visible
    WRITE_B();               // n0 piece (compiler waits bS loads)
    LBAR;                    // B visible
    ISSUE_B(kc, 1);          // n1 flies under compute
    COMPUTE(cur, 0);
    __builtin_amdgcn_s_barrier();   // all waves done reading B(n0)
    WRITE_B();               // n1 (compiler waits bS)
    if (kc < 7) {
      ISSUE_A(kc + 1);       // fly under compute(n1) + next writeA wait
      ISSUE_B(kc + 1, 0);
    }
    LBAR;                    // B(n1) visible
    COMPUTE(cur, 1);
    cur ^= 1;
  }
#undef ISSUE_A
#undef ISSUE_B
#undef WRITE_A
#undef WRITE_B
#undef COMPUTE
#undef LBAR

  // epilogue: + bias, cast fp16; C/D: col = lane&15, row = (lane>>4)*4 + r
#pragma unroll
  for (int m = 0; m < 8; m++) {
    const int row = m0 + m * 16 + g * 4;
#pragma unroll
    for (int h = 0; h < 2; h++)
#pragma unroll
      for (int nf = 0; nf < 2; nf++) {
        const int col = h * 256 + wave * 32 + nf * 16 + rl;
        const float bb = bias[col];
#pragma unroll
        for (int r = 0; r < 4; r++)
          out[(size_t)(row + r) * DHALF + col] = (f16)(acc[m][h * 2 + nf][r] + bb);
      }
  }
}

// ---------------------------------------------------------------------------
// Batched GEMM-TN: C[b] = A[b] (M x K, K-contig) * B[b] (K x N, N-contig).
// Template MI = M-fragments per wave (4 -> BM=128, 2 -> BM=64).
// B transpose-staged into [4k][16n] subtiles, phys order {0,2,4,6,1,3,5,7},
// read via ds_read_b64_tr_b16 (+offset:512).
// EPI=0: apply attn mask, store f32 logits.  EPI=1: store f32 to out.
// ---------------------------------------------------------------------------
template <int EPI, int MI>
__global__ __launch_bounds__(256, 3) void gemm_tn_kernel(
    const f16* __restrict__ A, long batchA, int lda,
    const f16* __restrict__ Bm, long batchB, int ldb,
    int Ksize,
    const int* __restrict__ mask,
    float* __restrict__ out, long batchOut, int ldo)
{
  constexpr int BM = MI * 32;            // block M-tile
  const int bz = blockIdx.z;
  const int n0 = blockIdx.x * 128;
  const int m0 = blockIdx.y * BM;
  const f16* Ab = A + (size_t)bz * batchA;
  const f16* Bb = Bm + (size_t)bz * batchB;

  const int tid = threadIdx.x, lane = tid & 63, wave = tid >> 6;
  const int wr = wave >> 1, wc = wave & 1;
  const int g = lane >> 4, rl = lane & 15;

  __shared__ f16 As[2][BM * 40];         // padded stride 40
  __shared__ f16 Bs[2][32 * 128];        // [n_blk(8)][phys(8)] blocks of [4][16]

  f32x4 acc[MI][4];
#pragma unroll
  for (int i = 0; i < MI; i++)
#pragma unroll
    for (int j = 0; j < 4; j++) acc[i][j] = (f32x4){0.f, 0.f, 0.f, 0.f};

  // A staging: BM*32 f16 by 256 threads
  const int arow = (MI == 4) ? (tid >> 1) : (tid >> 2);
  const int ah   = (MI == 4) ? ((tid & 1) * 16) : ((tid & 3) * 8);
  const int brow = tid >> 3;             // k-row 0..31
  const int bcol = (tid & 7) * 16;       // n offset
  const int sblk = brow >> 2;
  const int phys = ((sblk & 1) << 2) | (sblk >> 1);
  const int bwoff = ((tid & 7) * 8 + phys) * 128 + (brow & 3) * 32;  // bytes
  const f16* gA = Ab + (size_t)(m0 + arow) * lda + ah;
  const f16* gB = Bb + (size_t)brow * ldb + n0 + bcol;

  const unsigned bs_base = lds_off(&Bs[0][0]);

  f16x8 va0, va1, vb0, vb1;

#define GLOAD(K0)                                                       \
  va0 = *(const f16x8*)(gA + (K0));                                     \
  if (MI == 4) va1 = *(const f16x8*)(gA + (K0) + 8);                    \
  { const f16* gb = gB + (size_t)(K0) * ldb;                            \
    vb0 = *(const f16x8*)(gb);                                          \
    vb1 = *(const f16x8*)(gb + 8); }

#define GWRITE(BUF) {                                                   \
  *(f16x8*)&As[BUF][arow * 40 + ah] = va0;                              \
  if (MI == 4) *(f16x8*)&As[BUF][arow * 40 + ah + 8] = va1;             \
  char* wb = (char*)&Bs[BUF][0] + bwoff;                                \
  *(f16x8*)wb        = vb0;                                             \
  *(f16x8*)(wb + 16) = vb1; }

  GLOAD(0);
  GWRITE(0);
  __syncthreads();

  int cur = 0;
#pragma unroll 2
  for (int k0 = 0; k0 < Ksize; k0 += 32) {
    const bool more = (k0 + 32 < Ksize);
    if (more) { GLOAD(k0 + 32); }

    f16x8 af[MI];
#pragma unroll
    for (int i = 0; i < MI; i++)
      af[i] = *(const f16x8*)&As[cur][(wr * (MI * 16) + i * 16 + rl) * 40 + g * 8];

    f16x8 bf[4];
#pragma unroll
    for (int j = 0; j < 4; j++) {
      unsigned addr = bs_base + (unsigned)cur * 8192u +
                      (unsigned)((wc * 4 + j) * 1024) + (unsigned)lane * 8u;
      u32x2 lo, hi;
      asm volatile("ds_read_b64_tr_b16 %0, %1" : "=v"(lo) : "v"(addr));
      asm volatile("ds_read_b64_tr_b16 %0, %1 offset:512" : "=v"(hi) : "v"(addr));
      union { u32x4 u; f16x8 h; } cc;
      cc.u = (u32x4){lo.x, lo.y, hi.x, hi.y};
      bf[j] = cc.h;
    }
    // rule 18: fence tr-read results before register-only MFMA consumers
    asm volatile("s_waitcnt lgkmcnt(0)" ::: "memory");
    __builtin_amdgcn_sched_barrier(0);

#pragma unroll
    for (int i = 0; i < MI; i++)
#pragma unroll
      for (int j = 0; j < 4; j++)
        acc[i][j] = __builtin_amdgcn_mfma_f32_16x16x32_f16(af[i], bf[j], acc[i][j], 0, 0, 0);

    if (more) {
      GWRITE(cur ^ 1);
      __syncthreads();
      cur ^= 1;
    }
  }
#undef GLOAD
#undef GWRITE

  float* ob = out + (size_t)bz * batchOut;
#pragma unroll
  for (int i = 0; i < MI; i++) {
    const int row = m0 + wr * (MI * 16) + i * 16 + g * 4;
#pragma unroll
    for (int j = 0; j < 4; j++) {
      const int col = n0 + wc * 64 + j * 16 + rl;
#pragma unroll
      for (int r = 0; r < 4; r++) {
        float val = acc[i][j][r];
        if (EPI == 0) {
          if (mask[(row + r) * DHALF + col] != 0) val = -1e30f;
        }
        ob[(size_t)(row + r) * ldo + col] = val;
      }
    }
  }
}

// ---------------------------------------------------------------------------
// Row softmax over e (512) for 4096 rows; one wave per row; fp16 output.
// ---------------------------------------------------------------------------
__global__ __launch_bounds__(256) void softmax_kernel(
    const float* __restrict__ logits, f16* __restrict__ P)
{
  const int row  = blockIdx.x * 4 + (threadIdx.x >> 6);
  const int lane = threadIdx.x & 63;
  const float* rp = logits + (size_t)row * DHALF + lane * 8;
  f32x4 x0 = *(const f32x4*)rp;
  f32x4 x1 = *(const f32x4*)(rp + 4);

  float m = fmaxf(fmaxf(fmaxf(x0.x, x0.y), fmaxf(x0.z, x0.w)),
                  fmaxf(fmaxf(x1.x, x1.y), fmaxf(x1.z, x1.w)));
#pragma unroll
  for (int off = 32; off > 0; off >>= 1) m = fmaxf(m, __shfl_xor(m, off, 64));

  float e0 = __expf(x0.x - m), e1 = __expf(x0.y - m);
  float e2 = __expf(x0.z - m), e3 = __expf(x0.w - m);
  float e4 = __expf(x1.x - m), e5 = __expf(x1.y - m);
  float e6 = __expf(x1.z - m), e7 = __expf(x1.w - m);
  float s = ((e0 + e1) + (e2 + e3)) + ((e4 + e5) + (e6 + e7));
#pragma unroll
  for (int off = 32; off > 0; off >>= 1) s += __shfl_xor(s, off, 64);
  const float inv = 1.0f / s;

  union { h2_t h2[4]; f16x8 v; } o;
  o.h2[0] = __builtin_amdgcn_cvt_pkrtz(e0 * inv, e1 * inv);
  o.h2[1] = __builtin_amdgcn_cvt_pkrtz(e2 * inv, e3 * inv);
  o.h2[2] = __builtin_amdgcn_cvt_pkrtz(e4 * inv, e5 * inv);
  o.h2[3] = __builtin_amdgcn_cvt_pkrtz(e6 * inv, e7 * inv);
  *(f16x8*)(P + (size_t)row * DHALF + lane * 8) = o.v;
}

// ---------------------------------------------------------------------------
extern "C" void kernel_launch(void* const* d_in, const int* in_sizes, int n_in,
                              void* d_out, int out_size, void* d_ws, size_t ws_size,
                              hipStream_t stream) {
  const float* q    = (const float*)d_in[0];
  const float* k    = (const float*)d_in[1];
  const float* v    = (const float*)d_in[2];
  const int*   mask = (const int*)d_in[3];
  const float* Wq   = (const float*)d_in[4];
  const float* bq   = (const float*)d_in[5];
  const float* Wk   = (const float*)d_in[6];
  const float* bk   = (const float*)d_in[7];
  const float* Wv   = (const float*)d_in[8];
  const float* bv   = (const float*)d_in[9];

  char* ws = (char*)d_ws;
  f16*   qt     = (f16*)(ws);                                  // 16 MB
  f16*   kt     = (f16*)(ws + 16777216);                       // 16 MB
  f16*   vt     = (f16*)(ws + 2 * 16777216);                   // 16 MB
  float* logits = (float*)(ws + 3 * 16777216);                 // 8 MB
  f16*   P      = (f16*)(ws + 3 * 16777216 + 8388608);         // 4 MB
  // Wf16 (3 MB) overlaps the logits region: consumed by proj before QK writes logits
  f16*   Wf16   = (f16*)(ws + 3 * 16777216);

  // 0) preconvert weights to fp16
  wcvt_kernel<<<dim3(256, 3), 256, 0, stream>>>(Wq, Wk, Wv, Wf16);
  // 1) fused q/k/v projections -> fp16 (S,B,DH) flat; A read once, 512B runs
  proj_kernel<<<dim3(128, 1, 3), 512, 0, stream>>>(q, k, v, Wf16, bq, bk, bv,
                                                   qt, kt, vt);
  // 2) logits[b,d,e] = sum_s q_[b,d,s] k_[b,s,e]  (+mask -> -1e30), BM=64 -> 256 blocks
  gemm_tn_kernel<0, 2><<<dim3(4, 8, 8), 256, 0, stream>>>(
      qt, 1048576L, 2048, kt, 1048576L, 512, 2048, mask, logits, 262144L, 512);
  // 3) P = softmax(logits) over e, fp16
  softmax_kernel<<<dim3(1024), 256, 0, stream>>>(logits, P);
  // 4) out[b,d,s] = sum_e P[b,d,e] v_[b,e,s]  -> f32 d_out, BM=128 -> 512 blocks
  gemm_tn_kernel<1, 4><<<dim3(16, 4, 8), 256, 0, stream>>>(
      P, 262144L, 512, vt, 1048576L, 2048, 512, nullptr, (float*)d_out, 1048576L, 2048);
}